// Round 3
// baseline (60.517 us; speedup 1.0000x reference)
//
#include <hip/hip_runtime.h>

// Chamfer distance, B=4, N=M=8192, points (x,y,z) fp32.
// Strategy: all-pairs min via expansion f = |t|^2 - 2 p.t (add |p|^2 at end).
// One kernel does both directions (blockIdx.z), each block owns 64 rows
// exclusively and sweeps all columns -> no global atomics.

#define TILE_J 256   // columns staged in LDS per tile
#define RPT 8        // rows per thread

__global__ __launch_bounds__(256) void chamfer_pass(
    const float* __restrict__ pred,
    const float* __restrict__ target,
    float* __restrict__ partials,
    int N, int M)
{
    const int dir = blockIdx.z;
    const float* __restrict__ rows = (dir == 0) ? pred : target;
    const float* __restrict__ cols = (dir == 0) ? target : pred;
    const int nRows = (dir == 0) ? N : M;
    const int nCols = (dir == 0) ? M : N;

    __shared__ float4 sT[TILE_J];
    __shared__ float sPart[8];

    const int tid = threadIdx.x;
    const int tj  = tid & 31;   // column-lane within wave
    const int ti  = tid >> 5;   // row-group 0..7
    const int b   = blockIdx.y;

    const int rowBase = blockIdx.x * (RPT * 8) + ti * RPT;

    // load this thread's 8 rows into registers
    const float* rp = rows + ((size_t)b * nRows + rowBase) * 3;
    float px[RPT], py[RPT], pz[RPT], p2[RPT], mn[RPT];
#pragma unroll
    for (int r = 0; r < RPT; ++r) {
        px[r] = rp[3*r + 0];
        py[r] = rp[3*r + 1];
        pz[r] = rp[3*r + 2];
        p2[r] = px[r]*px[r] + py[r]*py[r] + pz[r]*pz[r];
        mn[r] = 3.4e38f;
    }

    const float* cb = cols + (size_t)b * nCols * 3;

    for (int jt = 0; jt < nCols; jt += TILE_J) {
        // stage TILE_J columns (one point per thread) as (x,y,z,|t|^2)
        const float* sp = cb + (size_t)(jt + tid) * 3;
        float x = sp[0], y = sp[1], z = sp[2];
        __syncthreads();   // previous tile fully consumed
        sT[tid] = make_float4(x, y, z, x*x + y*y + z*z);
        __syncthreads();

#pragma unroll
        for (int k = 0; k < 8; ++k) {
            float4 t = sT[tj + 32*k];
#pragma unroll
            for (int r = 0; r < RPT; ++r) {
                float c = px[r] * t.x;
                c = fmaf(py[r], t.y, c);
                c = fmaf(pz[r], t.z, c);
                float f = fmaf(-2.0f, c, t.w);
                mn[r] = fminf(mn[r], f);
            }
        }
    }

    // butterfly min across the 32 tj-lanes (same ti)
    float rs = 0.0f;
#pragma unroll
    for (int r = 0; r < RPT; ++r) {
        float v = mn[r];
        v = fminf(v, __shfl_xor(v, 16));
        v = fminf(v, __shfl_xor(v, 8));
        v = fminf(v, __shfl_xor(v, 4));
        v = fminf(v, __shfl_xor(v, 2));
        v = fminf(v, __shfl_xor(v, 1));
        rs += v + p2[r];   // dist for this row
    }

    if (tj == 0) sPart[ti] = rs;
    __syncthreads();
    if (tid == 0) {
        float s = 0.0f;
#pragma unroll
        for (int i = 0; i < 8; ++i) s += sPart[i];
        const float scale = 1.0f / ((float)gridDim.y * (float)nRows);
        const size_t bid = blockIdx.x +
            (size_t)gridDim.x * (blockIdx.y + (size_t)gridDim.y * blockIdx.z);
        partials[bid] = s * scale;
    }
}

__global__ __launch_bounds__(256) void chamfer_reduce(
    const float* __restrict__ partials, int n, float* __restrict__ out)
{
    __shared__ float s[256];
    float acc = 0.0f;
    for (int i = threadIdx.x; i < n; i += 256) acc += partials[i];
    s[threadIdx.x] = acc;
    __syncthreads();
    for (int w = 128; w > 0; w >>= 1) {
        if (threadIdx.x < w) s[threadIdx.x] += s[threadIdx.x + w];
        __syncthreads();
    }
    if (threadIdx.x == 0) out[0] = s[0];
}

extern "C" void kernel_launch(void* const* d_in, const int* in_sizes, int n_in,
                              void* d_out, int out_size, void* d_ws, size_t ws_size,
                              hipStream_t stream)
{
    const float* pred   = (const float*)d_in[0];
    const float* target = (const float*)d_in[1];
    float* out = (float*)d_out;

    const int B = 4;
    const int N = in_sizes[0] / (B * 3);   // 8192
    const int M = in_sizes[1] / (B * 3);   // 8192

    float* partials = (float*)d_ws;

    dim3 grid(N / (RPT * 8), B, 2);        // (128, 4, 2)
    chamfer_pass<<<grid, 256, 0, stream>>>(pred, target, partials, N, M);

    const int nPart = grid.x * grid.y * grid.z;  // 1024
    chamfer_reduce<<<1, 256, 0, stream>>>(partials, nPart, out);
}

// Round 7
// 55.403 us; speedup vs baseline: 1.0923x; 1.0923x over previous
//
#include <hip/hip_runtime.h>

// Chamfer distance, B=4, N=M=8192, points (x,y,z) fp32.
// d_ij = |p|^2 + |t|^2 - 2 p.t = 2*( (|t|^2/2 - p.t) ) + |p|^2.
// LDS stages (-x,-y,-z, |t|^2/2) so each pair is exactly 3 v_fma_f32;
// two columns share one v_min3_f32 -> 3.5 VALU instr/pair.

#define TILE_J 256   // columns staged in LDS per tile
#define RPT 8        // rows per thread

__global__ __launch_bounds__(256) void chamfer_pass(
    const float* __restrict__ pred,
    const float* __restrict__ target,
    float* __restrict__ partials,
    int N, int M)
{
    const int dir = blockIdx.z;
    const float* __restrict__ rows = (dir == 0) ? pred : target;
    const float* __restrict__ cols = (dir == 0) ? target : pred;
    const int nRows = (dir == 0) ? N : M;
    const int nCols = (dir == 0) ? M : N;

    __shared__ float4 sT[TILE_J];
    __shared__ float sPart[8];

    const int tid = threadIdx.x;
    const int tj  = tid & 31;   // column-lane within wave
    const int ti  = tid >> 5;   // row-group 0..7
    const int b   = blockIdx.y;

    const int rowBase = blockIdx.x * (RPT * 8) + ti * RPT;

    // load this thread's 8 rows into registers
    const float* rp = rows + ((size_t)b * nRows + rowBase) * 3;
    float px[RPT], py[RPT], pz[RPT], p2[RPT], mn[RPT];
#pragma unroll
    for (int r = 0; r < RPT; ++r) {
        px[r] = rp[3*r + 0];
        py[r] = rp[3*r + 1];
        pz[r] = rp[3*r + 2];
        p2[r] = px[r]*px[r] + py[r]*py[r] + pz[r]*pz[r];
        mn[r] = 3.4e38f;
    }

    const float* cb = cols + (size_t)b * nCols * 3;

    for (int jt = 0; jt < nCols; jt += TILE_J) {
        // stage TILE_J columns (one point per thread) as (-x,-y,-z, |t|^2/2)
        const float* sp = cb + (size_t)(jt + tid) * 3;
        float x = sp[0], y = sp[1], z = sp[2];
        __syncthreads();   // previous tile fully consumed
        sT[tid] = make_float4(-x, -y, -z, 0.5f * (x*x + y*y + z*z));
        __syncthreads();

#pragma unroll
        for (int k2 = 0; k2 < 4; ++k2) {
            float4 ta = sT[tj + 64*k2];
            float4 tb = sT[tj + 64*k2 + 32];
#pragma unroll
            for (int r = 0; r < RPT; ++r) {
                float ca = fmaf(px[r], ta.x, ta.w);
                ca = fmaf(py[r], ta.y, ca);
                ca = fmaf(pz[r], ta.z, ca);
                float cbv = fmaf(px[r], tb.x, tb.w);
                cbv = fmaf(py[r], tb.y, cbv);
                cbv = fmaf(pz[r], tb.z, cbv);
                // chained fminf -> v_min3_f32
                mn[r] = fminf(fminf(mn[r], ca), cbv);
            }
        }
    }

    // butterfly min across the 32 tj-lanes (same ti)
    float rs = 0.0f;
#pragma unroll
    for (int r = 0; r < RPT; ++r) {
        float v = mn[r];
        v = fminf(v, __shfl_xor(v, 16));
        v = fminf(v, __shfl_xor(v, 8));
        v = fminf(v, __shfl_xor(v, 4));
        v = fminf(v, __shfl_xor(v, 2));
        v = fminf(v, __shfl_xor(v, 1));
        rs += fmaf(2.0f, v, p2[r]);   // dist for this row
    }

    if (tj == 0) sPart[ti] = rs;
    __syncthreads();
    if (tid == 0) {
        float s = 0.0f;
#pragma unroll
        for (int i = 0; i < 8; ++i) s += sPart[i];
        const float scale = 1.0f / ((float)gridDim.y * (float)nRows);
        const size_t bid = blockIdx.x +
            (size_t)gridDim.x * (blockIdx.y + (size_t)gridDim.y * blockIdx.z);
        partials[bid] = s * scale;
    }
}

__global__ __launch_bounds__(256) void chamfer_reduce(
    const float* __restrict__ partials, int n, float* __restrict__ out)
{
    __shared__ float s[256];
    float acc = 0.0f;
    for (int i = threadIdx.x; i < n; i += 256) acc += partials[i];
    s[threadIdx.x] = acc;
    __syncthreads();
    for (int w = 128; w > 0; w >>= 1) {
        if (threadIdx.x < w) s[threadIdx.x] += s[threadIdx.x + w];
        __syncthreads();
    }
    if (threadIdx.x == 0) out[0] = s[0];
}

extern "C" void kernel_launch(void* const* d_in, const int* in_sizes, int n_in,
                              void* d_out, int out_size, void* d_ws, size_t ws_size,
                              hipStream_t stream)
{
    const float* pred   = (const float*)d_in[0];
    const float* target = (const float*)d_in[1];
    float* out = (float*)d_out;

    const int B = 4;
    const int N = in_sizes[0] / (B * 3);   // 8192
    const int M = in_sizes[1] / (B * 3);   // 8192

    float* partials = (float*)d_ws;

    dim3 grid(N / (RPT * 8), B, 2);        // (128, 4, 2)
    chamfer_pass<<<grid, 256, 0, stream>>>(pred, target, partials, N, M);

    const int nPart = grid.x * grid.y * grid.z;  // 1024
    chamfer_reduce<<<1, 256, 0, stream>>>(partials, nPart, out);
}

// Round 8
// 49.501 us; speedup vs baseline: 1.2225x; 1.1192x over previous
//
#include <hip/hip_runtime.h>

// Chamfer distance, B=4, N=M=8192, points (x,y,z) fp32.
// d_ij = |p|^2 + 2*( |t|^2/2 - p.t ).  LDS stages (-x,-y,-z,|t|^2/2) so each
// pair is 3 v_fma_f32; 2 columns share one v_min3_f32 -> 3.5 VALU instr/pair.
// RPT=16 so one ds_read_b128 feeds 16 rows (LDS pipe ~43% at VALU peak).
// Double-buffered staging: global loads issued before compute, ds_write after,
// one barrier per tile.

#define TILE_J 256   // columns staged in LDS per tile
#define RPT 16       // rows per thread

__global__ __launch_bounds__(256) void chamfer_pass(
    const float* __restrict__ pred,
    const float* __restrict__ target,
    float* __restrict__ partials,
    int N, int M)
{
    const int dir = blockIdx.z;
    const float* __restrict__ rows = (dir == 0) ? pred : target;
    const float* __restrict__ cols = (dir == 0) ? target : pred;
    const int nRows = (dir == 0) ? N : M;
    const int nCols = (dir == 0) ? M : N;

    __shared__ float4 sT[2][TILE_J];
    __shared__ float sPart[8];

    const int tid = threadIdx.x;
    const int tj  = tid & 31;   // column-lane within half-wave
    const int ti  = tid >> 5;   // row-group 0..7
    const int b   = blockIdx.y;

    const int rowBase = blockIdx.x * (RPT * 8) + ti * RPT;  // 128 rows/block

    // load this thread's 16 rows into registers
    const float* rp = rows + ((size_t)b * nRows + rowBase) * 3;
    float px[RPT], py[RPT], pz[RPT], mn[RPT];
#pragma unroll
    for (int r = 0; r < RPT; ++r) {
        px[r] = rp[3*r + 0];
        py[r] = rp[3*r + 1];
        pz[r] = rp[3*r + 2];
        mn[r] = 3.4e38f;
    }

    const float* cb = cols + (size_t)b * nCols * 3;
    const int NT = nCols / TILE_J;   // 32

    // prologue: stage tile 0
    {
        const float* sp = cb + (size_t)tid * 3;
        float x = sp[0], y = sp[1], z = sp[2];
        sT[0][tid] = make_float4(-x, -y, -z, 0.5f * (x*x + y*y + z*z));
    }
    __syncthreads();

    for (int t = 0; t < NT; ++t) {
        const int cur = t & 1;
        // issue next tile's global loads early (wraps to 0 on last iter; harmless)
        const int tn = (t + 1 < NT) ? (t + 1) : 0;
        const float* sp = cb + (size_t)(tn * TILE_J + tid) * 3;
        const float nx = sp[0], ny = sp[1], nz = sp[2];

        // compute on sT[cur]
#pragma unroll
        for (int k2 = 0; k2 < TILE_J / 64; ++k2) {
            const float4 ta = sT[cur][tj + 64*k2];
            const float4 tb = sT[cur][tj + 64*k2 + 32];
#pragma unroll
            for (int r = 0; r < RPT; ++r) {
                float ca = fmaf(px[r], ta.x, ta.w);
                ca = fmaf(py[r], ta.y, ca);
                ca = fmaf(pz[r], ta.z, ca);
                float cbv = fmaf(px[r], tb.x, tb.w);
                cbv = fmaf(py[r], tb.y, cbv);
                cbv = fmaf(pz[r], tb.z, cbv);
                mn[r] = fminf(fminf(mn[r], ca), cbv);   // -> v_min3_f32
            }
        }

        // write next tile into the other buffer; one barrier per tile
        sT[cur ^ 1][tid] = make_float4(-nx, -ny, -nz,
                                       0.5f * (nx*nx + ny*ny + nz*nz));
        __syncthreads();
    }

    // butterfly min across the 32 tj-lanes (same ti)
    float rs = 0.0f;
#pragma unroll
    for (int r = 0; r < RPT; ++r) {
        float v = mn[r];
        v = fminf(v, __shfl_xor(v, 16));
        v = fminf(v, __shfl_xor(v, 8));
        v = fminf(v, __shfl_xor(v, 4));
        v = fminf(v, __shfl_xor(v, 2));
        v = fminf(v, __shfl_xor(v, 1));
        const float p2 = px[r]*px[r] + py[r]*py[r] + pz[r]*pz[r];
        rs += fmaf(2.0f, v, p2);   // squared NN dist for this row
    }

    if (tj == 0) sPart[ti] = rs;
    __syncthreads();
    if (tid == 0) {
        float s = 0.0f;
#pragma unroll
        for (int i = 0; i < 8; ++i) s += sPart[i];
        const float scale = 1.0f / ((float)gridDim.y * (float)nRows);
        const size_t bid = blockIdx.x +
            (size_t)gridDim.x * (blockIdx.y + (size_t)gridDim.y * blockIdx.z);
        partials[bid] = s * scale;
    }
}

__global__ __launch_bounds__(256) void chamfer_reduce(
    const float* __restrict__ partials, int n, float* __restrict__ out)
{
    __shared__ float s[256];
    float acc = 0.0f;
    for (int i = threadIdx.x; i < n; i += 256) acc += partials[i];
    s[threadIdx.x] = acc;
    __syncthreads();
    for (int w = 128; w > 0; w >>= 1) {
        if (threadIdx.x < w) s[threadIdx.x] += s[threadIdx.x + w];
        __syncthreads();
    }
    if (threadIdx.x == 0) out[0] = s[0];
}

extern "C" void kernel_launch(void* const* d_in, const int* in_sizes, int n_in,
                              void* d_out, int out_size, void* d_ws, size_t ws_size,
                              hipStream_t stream)
{
    const float* pred   = (const float*)d_in[0];
    const float* target = (const float*)d_in[1];
    float* out = (float*)d_out;

    const int B = 4;
    const int N = in_sizes[0] / (B * 3);   // 8192
    const int M = in_sizes[1] / (B * 3);   // 8192

    float* partials = (float*)d_ws;

    dim3 grid(N / (RPT * 8), B, 2);        // (64, 4, 2) = 512 blocks
    chamfer_pass<<<grid, 256, 0, stream>>>(pred, target, partials, N, M);

    const int nPart = grid.x * grid.y * grid.z;  // 512
    chamfer_reduce<<<1, 256, 0, stream>>>(partials, nPart, out);
}

// Round 9
// 47.159 us; speedup vs baseline: 1.2833x; 1.0497x over previous
//
#include <hip/hip_runtime.h>

// Chamfer distance via MFMA (bf16 split-precision), B=4, N=M=8192, fp32 in/out.
//
// d_ij = |p|^2 + |t|^2 - 2 p.t.  Pack per-point 16-slot rows (K=16 of
// mfma_f32_32x32x16_bf16):
//   A-row (target t): [-2th(xyz), -2tl(xyz), -2th(xyz), -2tl(xyz), t2h, t2l, 0,0]
//   B-row (pred p):   [ ph(xyz),   ph(xyz),   pl(xyz),   pl(xyz),  1,   1,   0,0]
// where xh=bf16(x), xl=bf16(x-xh), t2=|t|^2 split likewise.  Then
//   sum_k A[k]*B[k] = t2 - 2*(th+tl).(ph+pl)   (all products exact in fp32)
// so one MFMA yields 32x32 of (d_ij - |p_j|^2); representation error ~2^-18.
// Min over targets: per-lane v_min3 tree over the 16 acc values, accumulate
// across 256 A-tiles, merge lane^32, add |p|^2, mean-reduce.

typedef short s8v __attribute__((ext_vector_type(8)));
typedef float f16v __attribute__((ext_vector_type(16)));

#define NPTS 8192
#define NB 4

__device__ inline unsigned short f2bf(float f) {          // fp32 -> bf16 (RNE)
    unsigned u = __builtin_bit_cast(unsigned, f);
    unsigned r = u + 0x7FFFu + ((u >> 16) & 1u);
    return (unsigned short)(r >> 16);
}
__device__ inline float bf2f(unsigned short s) {
    unsigned u = ((unsigned)s) << 16;
    return __builtin_bit_cast(float, u);
}
__device__ inline s8v load16(const unsigned short* p) {   // 8 bf16 = 16 B
    int4 v = *(const int4*)p;
    return __builtin_bit_cast(s8v, v);
}
__device__ inline float mintree(const f16v& a, float mn) { // 8 x v_min3_f32
    float m = fminf(fminf(a[0], a[1]), a[2]);
    m = fminf(fminf(m, a[3]), a[4]);
    m = fminf(fminf(m, a[5]), a[6]);
    m = fminf(fminf(m, a[7]), a[8]);
    m = fminf(fminf(m, a[9]), a[10]);
    m = fminf(fminf(m, a[11]), a[12]);
    m = fminf(fminf(m, a[13]), a[14]);
    return fminf(fminf(m, a[15]), mn);
}

// ---- prep: format both clouds into A-rows and B-rows in ws ----
// afmt[dir][b*NPTS+i]: A-source for dir0 = target(c=1), dir1 = pred(c=0) -> afmt[1-c]
// bfmt[dir][...]:      B-source for dir0 = pred(c=0),   dir1 = target(c=1) -> bfmt[c]
__global__ __launch_bounds__(256) void chamfer_prep(
    const float* __restrict__ pred, const float* __restrict__ target,
    unsigned short* __restrict__ afmt, unsigned short* __restrict__ bfmt)
{
    const int g = blockIdx.x * 256 + threadIdx.x;   // 0..65535
    const int c = g >> 15;
    const int rem = g & 32767;                      // b*NPTS + i
    const float* src = (c == 0 ? pred : target) + (size_t)rem * 3;
    const float x = src[0], y = src[1], z = src[2];

    const unsigned short phx = f2bf(x), phy = f2bf(y), phz = f2bf(z);
    const float thx = bf2f(phx), thy = bf2f(phy), thz = bf2f(phz);
    const unsigned short plx = f2bf(x - thx), ply = f2bf(y - thy), plz = f2bf(z - thz);
    const float t2 = x*x + y*y + z*z;
    const unsigned short t2h = f2bf(t2);
    const unsigned short t2l = f2bf(t2 - bf2f(t2h));

    union { unsigned short u[16]; int4 v[2]; } A, Bv;
    A.u[0] = f2bf(-2.f*thx); A.u[1] = f2bf(-2.f*thy); A.u[2] = f2bf(-2.f*thz);
    A.u[3] = f2bf(-2.f*bf2f(plx)); A.u[4] = f2bf(-2.f*bf2f(ply)); A.u[5] = f2bf(-2.f*bf2f(plz));
    A.u[6] = A.u[0]; A.u[7] = A.u[1]; A.u[8] = A.u[2];
    A.u[9] = A.u[3]; A.u[10] = A.u[4]; A.u[11] = A.u[5];
    A.u[12] = t2h; A.u[13] = t2l; A.u[14] = 0; A.u[15] = 0;

    Bv.u[0] = phx; Bv.u[1] = phy; Bv.u[2] = phz;
    Bv.u[3] = phx; Bv.u[4] = phy; Bv.u[5] = phz;
    Bv.u[6] = plx; Bv.u[7] = ply; Bv.u[8] = plz;
    Bv.u[9] = plx; Bv.u[10] = ply; Bv.u[11] = plz;
    Bv.u[12] = 0x3F80; Bv.u[13] = 0x3F80; Bv.u[14] = 0; Bv.u[15] = 0;

    int4* ap = (int4*)(afmt + ((size_t)(1 - c) * 32768 + rem) * 16);
    int4* bp = (int4*)(bfmt + ((size_t)c       * 32768 + rem) * 16);
    ap[0] = A.v[0]; ap[1] = A.v[1];
    bp[0] = Bv.v[0]; bp[1] = Bv.v[1];
}

// ---- main: 1 wave owns 64 preds, streams all 8192 targets ----
// A layout (32x32x16): lane row = lane&31, k = 8*(lane>>5)+j  -> 16B/lane/tile
// B layout: lane col = lane&31, k = 8*(lane>>5)+j
// C/D: col = lane&31 (pred), rows vary -> in-lane min is over targets. ✓
__global__ __launch_bounds__(256, 1) void chamfer_mfma(
    const float* __restrict__ pred, const float* __restrict__ target,
    const unsigned short* __restrict__ afmt,
    const unsigned short* __restrict__ bfmt,
    float* __restrict__ partials)
{
    const int dir = blockIdx.z;
    const int b   = blockIdx.y;
    const int wid = threadIdx.x >> 6;
    const int lane = threadIdx.x & 63;
    const int half = lane >> 5;
    const int l31  = lane & 31;
    const int pg   = blockIdx.x * 4 + wid;                 // 0..127

    const size_t cbase = ((size_t)dir * NB + b) * NPTS;    // formatted-row base

    const unsigned short* brow = bfmt + (cbase + (size_t)pg * 64) * 16;
    const s8v bf1 = load16(brow + (size_t)(l31 +  0) * 16 + half * 8);
    const s8v bf2 = load16(brow + (size_t)(l31 + 32) * 16 + half * 8);

    const float* pc = ((dir == 0) ? pred : target) + (size_t)b * NPTS * 3;
    const float* pa = pc + (size_t)(pg * 64 + l31) * 3;
    const float* pb = pc + (size_t)(pg * 64 + 32 + l31) * 3;
    const float p2a = pa[0]*pa[0] + pa[1]*pa[1] + pa[2]*pa[2];
    const float p2b = pb[0]*pb[0] + pb[1]*pb[1] + pb[2]*pb[2];

    const unsigned short* abase = afmt + cbase * 16;
    const int voff = l31 * 16 + half * 8;                  // ushort offset in tile

    f16v zf = {};                                          // zero C operand
    float mn1 = 1e30f, mn2 = 1e30f;

    // rolling prefetch, depth 8 (tile = 32 rows * 32 B = 512 ushorts)
    s8v a0 = load16(abase + 0*512 + voff);
    s8v a1 = load16(abase + 1*512 + voff);
    s8v a2 = load16(abase + 2*512 + voff);
    s8v a3 = load16(abase + 3*512 + voff);
    s8v a4 = load16(abase + 4*512 + voff);
    s8v a5 = load16(abase + 5*512 + voff);
    s8v a6 = load16(abase + 6*512 + voff);
    s8v a7 = load16(abase + 7*512 + voff);

#define PHASE(u, AV) { \
    f16v c1 = __builtin_amdgcn_mfma_f32_32x32x16_bf16(AV, bf1, zf, 0, 0, 0); \
    f16v c2 = __builtin_amdgcn_mfma_f32_32x32x16_bf16(AV, bf2, zf, 0, 0, 0); \
    AV = load16(abase + (size_t)(((t + 8 + u) & 255) * 512) + voff); \
    mn1 = mintree(c1, mn1); \
    mn2 = mintree(c2, mn2); }

    for (int t = 0; t < 256; t += 8) {
        PHASE(0, a0) PHASE(1, a1) PHASE(2, a2) PHASE(3, a3)
        PHASE(4, a4) PHASE(5, a5) PHASE(6, a6) PHASE(7, a7)
    }
#undef PHASE

    // merge the two row-halves (lane ^ 32 holds the other 16 target-rows)
    mn1 = fminf(mn1, __shfl_xor(mn1, 32));
    mn2 = fminf(mn2, __shfl_xor(mn2, 32));

    float rs = (mn1 + p2a) + (mn2 + p2b);                  // 2 preds' NN dist^2
    rs += __shfl_xor(rs, 16);
    rs += __shfl_xor(rs, 8);
    rs += __shfl_xor(rs, 4);
    rs += __shfl_xor(rs, 2);
    rs += __shfl_xor(rs, 1);                               // sum over 64 preds

    if (lane == 0)
        partials[(size_t)((dir * NB + b) * 128 + pg)] = rs * (1.0f / 32768.0f);
}

__global__ __launch_bounds__(256) void chamfer_reduce(
    const float* __restrict__ partials, int n, float* __restrict__ out)
{
    __shared__ float s[256];
    float acc = 0.0f;
    for (int i = threadIdx.x; i < n; i += 256) acc += partials[i];
    s[threadIdx.x] = acc;
    __syncthreads();
    for (int w = 128; w > 0; w >>= 1) {
        if (threadIdx.x < w) s[threadIdx.x] += s[threadIdx.x + w];
        __syncthreads();
    }
    if (threadIdx.x == 0) out[0] = s[0];
}

extern "C" void kernel_launch(void* const* d_in, const int* in_sizes, int n_in,
                              void* d_out, int out_size, void* d_ws, size_t ws_size,
                              hipStream_t stream)
{
    const float* pred   = (const float*)d_in[0];
    const float* target = (const float*)d_in[1];
    float* out = (float*)d_out;

    // ws layout: afmt 2 MB | bfmt 2 MB | partials 4 KB
    unsigned short* afmt = (unsigned short*)d_ws;
    unsigned short* bfmt = afmt + (size_t)2 * 32768 * 16;
    float* partials = (float*)((char*)d_ws + (size_t)4 * 1024 * 1024);

    chamfer_prep<<<256, 256, 0, stream>>>(pred, target, afmt, bfmt);

    dim3 grid(32, NB, 2);   // 32 blocks x 4 waves = 128 pred-groups per (b,dir)
    chamfer_mfma<<<grid, 256, 0, stream>>>(pred, target, afmt, bfmt, partials);

    chamfer_reduce<<<1, 256, 0, stream>>>(partials, 1024, out);
}

// Round 10
// 31.871 us; speedup vs baseline: 1.8988x; 1.4797x over previous
//
#include <hip/hip_runtime.h>

// Chamfer distance via MFMA (bf16 split-precision, exact products), fp32 in/out.
// B=4, N=M=8192.  d_ij = |p|^2 + |t|^2 - 2 p.t.
// A-row (target, prep-formatted): [-2th(xyz) -2tl(xyz) -2th(xyz) -2tl(xyz) t2h t2l 0 0]
// B-row (pred, built in-wave):    [ ph(xyz)   ph(xyz)   pl(xyz)   pl(xyz)  1   1  0 0]
// One mfma_f32_32x32x16_bf16 -> 32x32 of (d_ij - |p_j|^2), exact in fp32 up to
// bf16 split representation (~2^-18).
// v2: 8 target-chunks (occupancy 4 waves/SIMD), 2 pred-groups/wave (A reuse x4),
// linear double-buffered A prefetch.  Partial mins merged by chamfer_merge.

typedef short s8v __attribute__((ext_vector_type(8)));
typedef float f16v __attribute__((ext_vector_type(16)));

#define NPTS 8192
#define NB 4
#define CHUNKS 8          // target chunks of 1024 (32 tiles)

__device__ inline unsigned short f2bf(float f) {          // fp32 -> bf16 (RNE)
    unsigned u = __builtin_bit_cast(unsigned, f);
    unsigned r = u + 0x7FFFu + ((u >> 16) & 1u);
    return (unsigned short)(r >> 16);
}
__device__ inline float bf2f(unsigned short s) {
    unsigned u = ((unsigned)s) << 16;
    return __builtin_bit_cast(float, u);
}
__device__ inline s8v load16(const unsigned short* p) {   // 8 bf16 = 16 B
    int4 v = *(const int4*)p;
    return __builtin_bit_cast(s8v, v);
}
// fold 16 acc values + running min via v_min3 chain (8 instrs)
__device__ inline float mintree(const f16v& c, float mn) {
    float m = fminf(fminf(c[0], c[1]), c[2]);
    m = fminf(fminf(m, c[3]), c[4]);
    m = fminf(fminf(m, c[5]), c[6]);
    m = fminf(fminf(m, c[7]), c[8]);
    m = fminf(fminf(m, c[9]), c[10]);
    m = fminf(fminf(m, c[11]), c[12]);
    m = fminf(fminf(m, c[13]), c[14]);
    return fminf(fminf(m, c[15]), mn);
}

// ---- prep: format both clouds as A-rows ----
// slot (1-c): dir0 (pred->target) uses A=target (c=1 -> slot0);
//             dir1 uses A=pred   (c=0 -> slot1).
__global__ __launch_bounds__(256) void chamfer_prep(
    const float* __restrict__ pred, const float* __restrict__ target,
    unsigned short* __restrict__ afmt)
{
    const int g = blockIdx.x * 256 + threadIdx.x;   // 0..65535
    const int c = g >> 15;
    const int rem = g & 32767;                      // b*NPTS + i
    const float* src = (c == 0 ? pred : target) + (size_t)rem * 3;
    const float x = src[0], y = src[1], z = src[2];

    const unsigned short hx = f2bf(x), hy = f2bf(y), hz = f2bf(z);
    const float fx = bf2f(hx), fy = bf2f(hy), fz = bf2f(hz);
    const unsigned short lx = f2bf(x - fx), ly = f2bf(y - fy), lz = f2bf(z - fz);
    const float t2 = x*x + y*y + z*z;
    const unsigned short t2h = f2bf(t2);
    const unsigned short t2l = f2bf(t2 - bf2f(t2h));

    union { unsigned short u[16]; int4 v[2]; } A;
    A.u[0] = f2bf(-2.f*fx); A.u[1] = f2bf(-2.f*fy); A.u[2] = f2bf(-2.f*fz);
    A.u[3] = f2bf(-2.f*bf2f(lx)); A.u[4] = f2bf(-2.f*bf2f(ly)); A.u[5] = f2bf(-2.f*bf2f(lz));
    A.u[6] = A.u[0]; A.u[7] = A.u[1]; A.u[8] = A.u[2];
    A.u[9] = A.u[3]; A.u[10] = A.u[4]; A.u[11] = A.u[5];
    A.u[12] = t2h; A.u[13] = t2l; A.u[14] = 0; A.u[15] = 0;

    int4* ap = (int4*)(afmt + ((size_t)(1 - c) * 32768 + rem) * 16);
    ap[0] = A.v[0]; ap[1] = A.v[1];
}

// ---- main: wave owns 128 preds (4 col-blocks), streams 1 chunk (32 tiles) ----
__global__ __launch_bounds__(256, 4) void chamfer_mfma(
    const float* __restrict__ pred, const float* __restrict__ target,
    const unsigned short* __restrict__ afmt,
    float* __restrict__ pmins)
{
    const int dirb = blockIdx.y;            // dir*4 + b
    const int dir  = dirb >> 2;
    const int b    = dirb & 3;
    const int chunk = blockIdx.z;
    const int wid  = threadIdx.x >> 6;
    const int lane = threadIdx.x & 63;
    const int half = lane >> 5;
    const int l31  = lane & 31;
    const int w    = blockIdx.x * 4 + wid;  // 0..63
    const int base = w * 128;               // first pred of this wave

    // ---- build 4 B-frags in-register from raw coords ----
    const float* pc = ((dir == 0) ? pred : target) + (size_t)b * NPTS * 3;
    s8v bfrag[4];
#pragma unroll
    for (int q = 0; q < 4; ++q) {
        const float* sp = pc + (size_t)(base + q * 32 + l31) * 3;
        const float x = sp[0], y = sp[1], z = sp[2];
        const unsigned short hx = f2bf(x), hy = f2bf(y), hz = f2bf(z);
        const unsigned short lx = f2bf(x - bf2f(hx));
        const unsigned short ly = f2bf(y - bf2f(hy));
        const unsigned short lz = f2bf(z - bf2f(hz));
        union { unsigned short u[8]; s8v v; } F;
        if (half == 0) {
            F.u[0] = hx; F.u[1] = hy; F.u[2] = hz;
            F.u[3] = hx; F.u[4] = hy; F.u[5] = hz;
            F.u[6] = lx; F.u[7] = ly;
        } else {
            F.u[0] = lz; F.u[1] = lx; F.u[2] = ly; F.u[3] = lz;
            F.u[4] = 0x3F80; F.u[5] = 0x3F80; F.u[6] = 0; F.u[7] = 0;
        }
        bfrag[q] = F.v;
    }

    // ---- stream this chunk's 32 A-tiles (1 KB each), double-buffered ----
    const size_t cbase = ((size_t)dir * NB + b) * NPTS;
    const unsigned short* aptr = afmt + cbase * 16
        + (size_t)chunk * 32 * 512 + (l31 * 16 + half * 8);

    f16v zf = {};
    float mn[4] = {1e30f, 1e30f, 1e30f, 1e30f};

    s8v A0 = load16(aptr + 0*512), A1 = load16(aptr + 1*512),
        A2 = load16(aptr + 2*512), A3 = load16(aptr + 3*512);
    s8v N0, N1, N2, N3;

#define TILE(AV) { \
    f16v c0 = __builtin_amdgcn_mfma_f32_32x32x16_bf16(AV, bfrag[0], zf, 0,0,0); \
    f16v c1 = __builtin_amdgcn_mfma_f32_32x32x16_bf16(AV, bfrag[1], zf, 0,0,0); \
    mn[0] = mintree(c0, mn[0]); \
    f16v c2 = __builtin_amdgcn_mfma_f32_32x32x16_bf16(AV, bfrag[2], zf, 0,0,0); \
    mn[1] = mintree(c1, mn[1]); \
    f16v c3 = __builtin_amdgcn_mfma_f32_32x32x16_bf16(AV, bfrag[3], zf, 0,0,0); \
    mn[2] = mintree(c2, mn[2]); \
    mn[3] = mintree(c3, mn[3]); }

#pragma unroll
    for (int g = 0; g < 8; ++g) {
        if (g < 7) {
            N0 = load16(aptr + 2048 + 0*512);
            N1 = load16(aptr + 2048 + 1*512);
            N2 = load16(aptr + 2048 + 2*512);
            N3 = load16(aptr + 2048 + 3*512);
        }
        TILE(A0) TILE(A1) TILE(A2) TILE(A3)
        if (g < 7) { A0 = N0; A1 = N1; A2 = N2; A3 = N3; aptr += 2048; }
    }
#undef TILE

    // merge row-halves: lane^32 holds the other 16 target-rows
#pragma unroll
    for (int q = 0; q < 4; ++q) mn[q] = fminf(mn[q], __shfl_xor(mn[q], 32));

    // write partial mins (one float per pred per chunk)
    if (half == 0) {
        float* dst = pmins + ((size_t)dirb * CHUNKS + chunk) * NPTS + base + l31;
        dst[0]  = mn[0];
        dst[32] = mn[1];
        dst[64] = mn[2];
        dst[96] = mn[3];
    }
}

// ---- merge chunks, add |p|^2, partial-sum ----
__global__ __launch_bounds__(256) void chamfer_merge(
    const float* __restrict__ pred, const float* __restrict__ target,
    const float* __restrict__ pmins, float* __restrict__ partials)
{
    const int t = blockIdx.x * 256 + threadIdx.x;   // 0..65535
    const int dirb = t >> 13;
    const int pr   = t & 8191;
    const int dir  = dirb >> 2;
    const int b    = dirb & 3;

    const float* mrow = pmins + (size_t)dirb * CHUNKS * NPTS + pr;
    float m = fminf(fminf(mrow[0*NPTS], mrow[1*NPTS]), mrow[2*NPTS]);
    m = fminf(fminf(m, mrow[3*NPTS]), mrow[4*NPTS]);
    m = fminf(fminf(m, mrow[5*NPTS]), mrow[6*NPTS]);
    m = fminf(m, mrow[7*NPTS]);

    const float* sp = ((dir == 0) ? pred : target) + ((size_t)b * NPTS + pr) * 3;
    const float p2 = sp[0]*sp[0] + sp[1]*sp[1] + sp[2]*sp[2];
    float v = (m + p2) * (1.0f / 32768.0f);

    __shared__ float s[256];
    s[threadIdx.x] = v;
    __syncthreads();
    for (int wd = 128; wd > 0; wd >>= 1) {
        if (threadIdx.x < wd) s[threadIdx.x] += s[threadIdx.x + wd];
        __syncthreads();
    }
    if (threadIdx.x == 0) partials[blockIdx.x] = s[0];
}

__global__ __launch_bounds__(256) void chamfer_reduce(
    const float* __restrict__ partials, int n, float* __restrict__ out)
{
    __shared__ float s[256];
    float acc = 0.0f;
    for (int i = threadIdx.x; i < n; i += 256) acc += partials[i];
    s[threadIdx.x] = acc;
    __syncthreads();
    for (int w = 128; w > 0; w >>= 1) {
        if (threadIdx.x < w) s[threadIdx.x] += s[threadIdx.x + w];
        __syncthreads();
    }
    if (threadIdx.x == 0) out[0] = s[0];
}

extern "C" void kernel_launch(void* const* d_in, const int* in_sizes, int n_in,
                              void* d_out, int out_size, void* d_ws, size_t ws_size,
                              hipStream_t stream)
{
    const float* pred   = (const float*)d_in[0];
    const float* target = (const float*)d_in[1];
    float* out = (float*)d_out;

    // ws: afmt 2 MB | pmins 2 MB | partials 1 KB
    unsigned short* afmt = (unsigned short*)d_ws;
    float* pmins    = (float*)((char*)d_ws + (size_t)2 * 1024 * 1024);
    float* partials = (float*)((char*)d_ws + (size_t)4 * 1024 * 1024);

    chamfer_prep<<<256, 256, 0, stream>>>(pred, target, afmt);

    dim3 grid(16, 8, CHUNKS);   // 1024 blocks, 4 waves each
    chamfer_mfma<<<grid, 256, 0, stream>>>(pred, target, afmt, pmins);

    chamfer_merge<<<256, 256, 0, stream>>>(pred, target, pmins, partials);
    chamfer_reduce<<<1, 256, 0, stream>>>(partials, 256, out);
}